// Round 7
// baseline (34951.886 us; speedup 1.0000x reference)
//
#include <hip/hip_runtime.h>
#include <stdint.h>
#include <stddef.h>

typedef _Float16 f16;
typedef _Float16 half2_t __attribute__((ext_vector_type(2)));
typedef _Float16 half8_t __attribute__((ext_vector_type(8)));
typedef float   float4_t __attribute__((ext_vector_type(4)));
typedef float   float2_t __attribute__((ext_vector_type(2)));

#define T_STEPS 8192

// ---------------- workspace layout (bytes) ----------------
#define OFF_ZX   ((size_t)0)                    // Zx0 f16 [8192][4096]        = 67108864
#define OFF_HS   ((size_t)67108864)             // hs  f16 [8192][1024]        = 16777216
#define OFF_R0A  ((size_t)83886080)             // h0  u64[8 rep][8 slot][512] = 262144
#define OFF_R0B  (OFF_R0A + 262144)             // h0  u64[8 rep][16][512]     = 524288 (-> G1X)
#define OFF_R1A  (OFF_R0B + 524288)             // h1  u64[8 rep][8][512]      = 262144
#define OFF_ZR   (OFF_R1A + 262144)             // z1x u64[4 rep][16][4096]    = 2097152 (f32 payload)
#define OFF_PG0  (OFF_ZR + 2097152)             // prog0 u32[128]x16 stride    = 8192
#define OFF_PG1  (OFF_PG0 + 8192)               // prog1 u32[32]x16 stride     = 2048
#define OFF_XC   (OFF_PG1 + 2048)               // xcd registry u32[256]       = 1024
#define ZERO_BYTES ((size_t)(OFF_XC + 1024 - OFF_R0A))   // 3,156,992

__device__ __forceinline__ uint32_t packh(float a, float b) {
  half2_t h; h.x = (_Float16)a; h.y = (_Float16)b;
  return __builtin_bit_cast(uint32_t, h);
}
__device__ __forceinline__ float fdot2w(uint32_t w, uint32_t h, float c) {
#if __has_builtin(__builtin_amdgcn_fdot2)
  return __builtin_amdgcn_fdot2(__builtin_bit_cast(half2_t, w),
                                __builtin_bit_cast(half2_t, h), c, false);
#else
  half2_t a = __builtin_bit_cast(half2_t, w);
  half2_t b = __builtin_bit_cast(half2_t, h);
  return c + (float)a.x * (float)b.x + (float)a.y * (float)b.y;
#endif
}
__device__ __forceinline__ uint64_t ald64(const uint64_t* p) {
  return __hip_atomic_load(p, __ATOMIC_RELAXED, __HIP_MEMORY_SCOPE_AGENT);
}
__device__ __forceinline__ void ast64(uint64_t* p, uint64_t v) {
  __hip_atomic_store(p, v, __ATOMIC_RELAXED, __HIP_MEMORY_SCOPE_AGENT);
}
__device__ __forceinline__ uint32_t ald32(const uint32_t* p) {
  return __hip_atomic_load(p, __ATOMIC_RELAXED, __HIP_MEMORY_SCOPE_AGENT);
}
__device__ __forceinline__ void ast32(uint32_t* p, uint32_t v) {
  __hip_atomic_store(p, v, __ATOMIC_RELAXED, __HIP_MEMORY_SCOPE_AGENT);
}
__device__ __forceinline__ uint32_t xcc_id() {
  uint32_t x;
  asm("s_getreg_b32 %0, hwreg(20, 0, 4)" : "=s"(x));  // HW_REG_XCC_ID
  return x;
}
// hot poll: serial-critical rings, pure agent loads, no backoff
__device__ __forceinline__ uint32_t poll_a(const uint64_t* p, uint32_t tag) {
  for (;;) {
    uint64_t v = ald64(p);
    if ((uint32_t)(v >> 32) == tag) return (uint32_t)v;
  }
}
// slack poll: pipelined streams, light backoff
__device__ __forceinline__ uint32_t poll_s(const uint64_t* p, uint32_t tag) {
  int it = 0;
  for (;;) {
    uint64_t v = ald64(p);
    if ((uint32_t)(v >> 32) == tag) return (uint32_t)v;
    if ((++it & 15) == 15) __builtin_amdgcn_s_sleep(1);
  }
}
__device__ __forceinline__ float sel8(const float a[8], int k) {
  float x0 = (k & 1) ? a[1] : a[0], x1 = (k & 1) ? a[3] : a[2];
  float x2 = (k & 1) ? a[5] : a[4], x3 = (k & 1) ? a[7] : a[6];
  float y0 = (k & 2) ? x1 : x0, y1 = (k & 2) ? x3 : x2;
  return (k & 4) ? y1 : y0;
}
__device__ __forceinline__ float sigf(float x) { return 1.f / (1.f + __expf(-x)); }
__device__ __forceinline__ float tanhf_(float x) { return 2.f * sigf(2.f * x) - 1.f; }

__global__ void k_init(uint64_t* __restrict__ Z) {
  size_t n = ZERO_BYTES / 8;
  for (size_t i = blockIdx.x * blockDim.x + threadIdx.x; i < n;
       i += (size_t)gridDim.x * blockDim.x)
    Z[i] = 0ull;
}

// ---------------- generic 128x128 MFMA f16 GEMM (unchanged) ----------------
template <bool A16, bool OUT16>
__global__ __launch_bounds__(256) void k_gemm(const void* __restrict__ Ap,
                                              const float* __restrict__ B,
                                              const float* __restrict__ bias0,
                                              const float* __restrict__ bias1,
                                              void* __restrict__ Cp,
                                              int N, int K, int lda) {
  __shared__ __align__(16) f16 As[128 * 40];
  __shared__ __align__(16) f16 Bs[128 * 40];
  int bn = blockIdx.x * 128, bm = blockIdx.y * 128;
  int tid = threadIdx.x;
  int w = tid >> 6, l = tid & 63;
  int m0w = (w >> 1) * 64, n0w = (w & 1) * 64;
  int lr = l & 15, q = l >> 4;
  int srow = tid >> 1, skoff = (tid & 1) * 16;

  float4_t acc[4][4];
#pragma unroll
  for (int i = 0; i < 4; ++i)
#pragma unroll
    for (int j = 0; j < 4; ++j) acc[i][j] = (float4_t){0.f, 0.f, 0.f, 0.f};

  for (int kt = 0; kt < K; kt += 32) {
    __syncthreads();
    if (A16) {
      const f16* Ah = (const f16*)Ap + (size_t)(bm + srow) * lda + kt + skoff;
      uint4 u0 = *(const uint4*)Ah;
      uint4 u1 = *(const uint4*)(Ah + 8);
      *(uint4*)&As[srow * 40 + skoff] = u0;
      *(uint4*)&As[srow * 40 + skoff + 8] = u1;
    } else {
      const float* Af = (const float*)Ap + (size_t)(bm + srow) * lda + kt + skoff;
      const float4_t* A4 = (const float4_t*)Af;
      float4_t f0 = A4[0], f1 = A4[1], f2 = A4[2], f3 = A4[3];
      half8_t h0 = {(f16)f0.x, (f16)f0.y, (f16)f0.z, (f16)f0.w,
                    (f16)f1.x, (f16)f1.y, (f16)f1.z, (f16)f1.w};
      half8_t h1 = {(f16)f2.x, (f16)f2.y, (f16)f2.z, (f16)f2.w,
                    (f16)f3.x, (f16)f3.y, (f16)f3.z, (f16)f3.w};
      *(half8_t*)&As[srow * 40 + skoff] = h0;
      *(half8_t*)&As[srow * 40 + skoff + 8] = h1;
    }
    {
      const float* Bf = B + (size_t)(bn + srow) * K + kt + skoff;
      const float4_t* B4 = (const float4_t*)Bf;
      float4_t f0 = B4[0], f1 = B4[1], f2 = B4[2], f3 = B4[3];
      half8_t h0 = {(f16)f0.x, (f16)f0.y, (f16)f0.z, (f16)f0.w,
                    (f16)f1.x, (f16)f1.y, (f16)f1.z, (f16)f1.w};
      half8_t h1 = {(f16)f2.x, (f16)f2.y, (f16)f2.z, (f16)f2.w,
                    (f16)f3.x, (f16)f3.y, (f16)f3.z, (f16)f3.w};
      *(half8_t*)&Bs[srow * 40 + skoff] = h0;
      *(half8_t*)&Bs[srow * 40 + skoff + 8] = h1;
    }
    __syncthreads();
    half8_t af[4], bf[4];
#pragma unroll
    for (int i = 0; i < 4; ++i) af[i] = *(const half8_t*)&As[(m0w + 16 * i + lr) * 40 + q * 8];
#pragma unroll
    for (int j = 0; j < 4; ++j) bf[j] = *(const half8_t*)&Bs[(n0w + 16 * j + lr) * 40 + q * 8];
#pragma unroll
    for (int i = 0; i < 4; ++i)
#pragma unroll
      for (int j = 0; j < 4; ++j)
        acc[i][j] = __builtin_amdgcn_mfma_f32_16x16x32_f16(af[i], bf[j], acc[i][j], 0, 0, 0);
  }
#pragma unroll
  for (int j = 0; j < 4; ++j) {
    int n = bn + n0w + 16 * j + lr;
    float bv = bias0 ? bias0[n] : 0.f;
    if (bias1) bv += bias1[n];
#pragma unroll
    for (int i = 0; i < 4; ++i) {
#pragma unroll
      for (int r = 0; r < 4; ++r) {
        int m = bm + m0w + 16 * i + q * 4 + r;
        float v = acc[i][j][r] + bv;
        if (OUT16) ((f16*)Cp)[(size_t)m * N + n] = (f16)v;
        else       ((float*)Cp)[(size_t)m * N + n] = v;
      }
    }
  }
}

// ================= L0: layer-0 serial, 32 blocks (XCD role 0) =================
// Wave w owns outputs 2w,2w+1 (block offset O=32r): 8 rows in VGPRs, in-wave gates.
__device__ __forceinline__ void run_l0(int r, const f16* Zx, const float* whh0,
                                       uint64_t* R0A, uint64_t* R0B,
                                       const uint32_t* prog0) {
  __shared__ uint32_t hL[512];
  int tid = threadIdx.x, w = tid >> 6, l = tid & 63;
  int O = 32 * r;
  uint32_t wr[64];
#pragma unroll
  for (int g = 0; g < 4; ++g)
#pragma unroll
    for (int dd = 0; dd < 2; ++dd) {
      size_t R = (size_t)(1024 * g + O + 2 * w + dd) * 1024;
#pragma unroll
      for (int p = 0; p < 8; ++p) {
        int k = l + 64 * p;
        float2_t u = *(const float2_t*)&whh0[R + 2 * k];
        wr[(2 * g + dd) * 8 + p] = packh(u.x, u.y);
      }
    }
  float c0 = 0.f;
  float zx = 0.f;  // lane l<8 holds Zx for (g=l>>1, delta=l&1)
  if (l < 8) zx = (float)Zx[(size_t)1024 * (l >> 1) + O + 2 * w + (l & 1)];

  for (int t = 0; t < T_STEPS; ++t) {
    float zn = 0.f;
    if (l < 8 && t + 1 < T_STEPS)
      zn = (float)Zx[(size_t)(t + 1) * 4096 + 1024 * (l >> 1) + O + 2 * w + (l & 1)];
    // throttle vs G1X consumption of R0B (depth 16, check every 4 phases)
    if (w == 8 && l == 0 && (t & 3) == 0) {
#pragma unroll
      for (int j = 0; j < 4; ++j) {
        const uint32_t* pp = prog0 + (4 * r + j) * 16;
        while ((int)ald32(pp) < t - 8) __builtin_amdgcn_s_sleep(2);
      }
    }
    if (w < 8)
      hL[tid] = poll_a(&R0A[((size_t)(r & 7) * 8 + (size_t)(t & 7)) * 512 + tid],
                       (uint32_t)t);
    __syncthreads();
    uint32_t hw[8];
#pragma unroll
    for (int p = 0; p < 8; ++p) hw[p] = hL[l + 64 * p];
    float acc[8];
#pragma unroll
    for (int j = 0; j < 8; ++j) acc[j] = 0.f;
#pragma unroll
    for (int j = 0; j < 8; ++j)
#pragma unroll
      for (int p = 0; p < 8; ++p) acc[j] = fdot2w(wr[j * 8 + p], hw[p], acc[j]);
#pragma unroll
    for (int d = 1; d < 64; d <<= 1)
#pragma unroll
      for (int j = 0; j < 8; ++j) acc[j] += __shfl_xor(acc[j], d);
    int dd = l & 1;
    float zi_ = __shfl(zx, dd), zf_ = __shfl(zx, 2 + dd);
    float zg_ = __shfl(zx, 4 + dd), zo_ = __shfl(zx, 6 + dd);
    float h = 0.f;
    if (l < 2) {
      float si = (dd ? acc[1] : acc[0]) + zi_;
      float sf = (dd ? acc[3] : acc[2]) + zf_;
      float sg = (dd ? acc[5] : acc[4]) + zg_;
      float so = (dd ? acc[7] : acc[6]) + zo_;
      float ig = sigf(si), fg = sigf(sf), gg = tanhf_(sg), og = sigf(so);
      c0 = fg * c0 + ig * gg;
      h = og * tanhf_(c0);
    }
    float ho = __shfl(h, 1);
    uint32_t pr = packh(h, ho);
    uint32_t pj = __shfl(pr, 0);
    uint64_t val = ((uint64_t)(uint32_t)(t + 1) << 32) | (uint64_t)pj;
    int ent = 16 * r + w;
    if (l < 8)
      ast64(&R0A[((size_t)l * 8 + (size_t)((t + 1) & 7)) * 512 + ent], val);
    else if (l < 16)
      ast64(&R0B[((size_t)(l - 8) * 16 + (size_t)((t + 1) & 15)) * 512 + ent], val);
    zx = zn;
    __syncthreads();
  }
}

// ================= G1: layer-1 serial, 32 blocks (XCD role 1) =================
__device__ __forceinline__ void run_g1(int q, const float* whh1, const float* b_ih1,
                                       const float* b_hh1, uint64_t* R1A,
                                       const uint64_t* ZR, f16* hs,
                                       uint32_t* prog1) {
  __shared__ uint32_t hL[512];
  __shared__ uint32_t zxL[128];
  int tid = threadIdx.x, w = tid >> 6, l = tid & 63;
  int O = 32 * q;
  uint32_t wr[64];
#pragma unroll
  for (int g = 0; g < 4; ++g)
#pragma unroll
    for (int dd = 0; dd < 2; ++dd) {
      size_t R = (size_t)(1024 * g + O + 2 * w + dd) * 1024;
#pragma unroll
      for (int p = 0; p < 8; ++p) {
        int k = l + 64 * p;
        float2_t u = *(const float2_t*)&whh1[R + 2 * k];
        wr[(2 * g + dd) * 8 + p] = packh(u.x, u.y);
      }
    }
  float c1 = 0.f;
  float bv0 = 0.f, bv1 = 0.f, bv2 = 0.f, bv3 = 0.f;
  if (l < 2) {
    int base = O + 2 * w + l;
    bv0 = b_ih1[base] + b_hh1[base];
    bv1 = b_ih1[1024 + base] + b_hh1[1024 + base];
    bv2 = b_ih1[2048 + base] + b_hh1[2048 + base];
    bv3 = b_ih1[3072 + base] + b_hh1[3072 + base];
  }

  for (int t = 0; t < T_STEPS; ++t) {
    if (w < 8) {
      hL[tid] = poll_a(&R1A[((size_t)(q & 7) * 8 + (size_t)(t & 7)) * 512 + tid],
                       (uint32_t)t);
    } else if (w == 8 || w == 9) {  // z1x stream (f32 payload): 128 entries
      int idx = (w - 8) * 64 + l;
      int g = idx >> 5, r5 = idx & 31;
      zxL[idx] = poll_s(&ZR[((size_t)(q & 3) * 16 + (size_t)((t + 1) & 15)) * 4096
                            + 1024 * g + O + r5],
                        (uint32_t)(t + 1));
    }
    __syncthreads();
    if (tid == 960) ast32(prog1 + q * 16, (uint32_t)(t + 1));
    uint32_t hw[8];
#pragma unroll
    for (int p = 0; p < 8; ++p) hw[p] = hL[l + 64 * p];
    float acc[8];
#pragma unroll
    for (int j = 0; j < 8; ++j) acc[j] = 0.f;
#pragma unroll
    for (int j = 0; j < 8; ++j)
#pragma unroll
      for (int p = 0; p < 8; ++p) acc[j] = fdot2w(wr[j * 8 + p], hw[p], acc[j]);
#pragma unroll
    for (int d = 1; d < 64; d <<= 1)
#pragma unroll
      for (int j = 0; j < 8; ++j) acc[j] += __shfl_xor(acc[j], d);
    int dd = l & 1;
    float z_i = __builtin_bit_cast(float, zxL[2 * w + dd]);
    float z_f = __builtin_bit_cast(float, zxL[32 + 2 * w + dd]);
    float z_g = __builtin_bit_cast(float, zxL[64 + 2 * w + dd]);
    float z_o = __builtin_bit_cast(float, zxL[96 + 2 * w + dd]);
    float h = 0.f;
    if (l < 2) {
      float si = (dd ? acc[1] : acc[0]) + z_i + bv0;
      float sf = (dd ? acc[3] : acc[2]) + z_f + bv1;
      float sg = (dd ? acc[5] : acc[4]) + z_g + bv2;
      float so = (dd ? acc[7] : acc[6]) + z_o + bv3;
      float ig = sigf(si), fg = sigf(sf), gg = tanhf_(sg), og = sigf(so);
      c1 = fg * c1 + ig * gg;
      h = og * tanhf_(c1);
    }
    float ho = __shfl(h, 1);
    uint32_t pr = packh(h, ho);
    uint32_t pj = __shfl(pr, 0);
    if (l == 0) ((uint32_t*)hs)[(size_t)t * 512 + 16 * q + w] = pj;
    uint64_t val = ((uint64_t)(uint32_t)(t + 1) << 32) | (uint64_t)pj;
    int ent = 16 * q + w;
    if (l < 8)
      ast64(&R1A[((size_t)l * 8 + (size_t)((t + 1) & 7)) * 512 + ent], val);
    __syncthreads();
  }
}

// ================= G1X: z1x = w_ih1 @ h0 stream, 4 cohorts x 32 blocks =================
__device__ __forceinline__ void run_g1x(int c, int s, const float* wih1,
                                        const uint64_t* R0B, uint64_t* ZR,
                                        uint32_t* prog0, const uint32_t* prog1) {
  __shared__ uint32_t hL[512];
  int tid = threadIdx.x, w = tid >> 6, l = tid & 63;
  int RB = 128 * s;  // rows RB..RB+127
  uint32_t wr[64];
#pragma unroll
  for (int j = 0; j < 8; ++j) {
    size_t R = (size_t)(RB + 8 * w + j) * 1024;
#pragma unroll
    for (int p = 0; p < 8; ++p) {
      int k = l + 64 * p;
      float2_t u = *(const float2_t*)&wih1[R + 2 * k];
      wr[j * 8 + p] = packh(u.x, u.y);
    }
  }
  int u_ = c * 32 + s;
  for (int t = c; t < T_STEPS; t += 4) {
    if (w == 8 && l == 0) {  // throttle vs G1 consumption of ZR (depth 16)
      const uint32_t* pp = prog1 + s * 16;
      while ((int)ald32(pp) < t - 8) __builtin_amdgcn_s_sleep(2);
    }
    if (w < 8)
      hL[tid] = poll_s(&R0B[((size_t)(s & 7) * 16 + (size_t)((t + 1) & 15)) * 512 + tid],
                       (uint32_t)(t + 1));
    __syncthreads();
    if (tid == 960) ast32(prog0 + u_ * 16, (uint32_t)(t + 1));
    uint32_t hw[8];
#pragma unroll
    for (int p = 0; p < 8; ++p) hw[p] = hL[l + 64 * p];
    float acc[8];
#pragma unroll
    for (int j = 0; j < 8; ++j) acc[j] = 0.f;
#pragma unroll
    for (int j = 0; j < 8; ++j)
#pragma unroll
      for (int p = 0; p < 8; ++p) acc[j] = fdot2w(wr[j * 8 + p], hw[p], acc[j]);
#pragma unroll
    for (int d = 1; d < 64; d <<= 1)
#pragma unroll
      for (int j = 0; j < 8; ++j) acc[j] += __shfl_xor(acc[j], d);
    // publish f32 z rows: lane k<32 -> row RB+8w+(k&7), replica k>>3
    float zv = sel8(acc, l & 7);
    if (l < 32) {
      uint64_t val = ((uint64_t)(uint32_t)(t + 1) << 32)
                   | (uint64_t)__builtin_bit_cast(uint32_t, zv);
      ast64(&ZR[((size_t)(l >> 3) * 16 + (size_t)((t + 1) & 15)) * 4096
                + RB + 8 * w + (l & 7)],
            val);
    }
    __syncthreads();
  }
}

__global__ __launch_bounds__(1024, 1) void k_serial(
    const f16* __restrict__ Zx, const float* __restrict__ whh0,
    const float* __restrict__ wih1, const float* __restrict__ whh1,
    const float* __restrict__ b_ih1, const float* __restrict__ b_hh1,
    f16* __restrict__ hs, uint64_t* __restrict__ R0A, uint64_t* __restrict__ R0B,
    uint64_t* __restrict__ R1A, uint64_t* __restrict__ ZR,
    uint32_t* __restrict__ prog0, uint32_t* __restrict__ prog1,
    uint32_t* __restrict__ xc) {
  __shared__ int srole[2];
  if (threadIdx.x == 0) {
    uint32_t xcd = xcc_id() & 7u;
    uint32_t rk = atomicAdd(&xc[xcd * 16], 1u);
    atomicOr(&xc[128], 1u << xcd);
    atomicAdd(&xc[129], 1u);
    while (ald32(&xc[129]) < (uint32_t)gridDim.x) __builtin_amdgcn_s_sleep(8);
    uint32_t mask = ald32(&xc[128]);
    srole[0] = __popc(mask & ((1u << xcd) - 1u));  // dense xcd index
    srole[1] = (int)rk;
  }
  __syncthreads();
  int dense = srole[0], rk = srole[1];
  if (rk >= 32) return;
  if (dense == 0)      run_l0(rk, Zx, whh0, R0A, R0B, prog0);
  else if (dense == 1) run_g1(rk, whh1, b_ih1, b_hh1, R1A, ZR, hs, prog1);
  else if (dense >= 2 && dense <= 5)
    run_g1x(dense - 2, rk, wih1, R0B, ZR, prog0, prog1);
  // dense 6,7: spare XCDs, idle
}

// ---------------- value head ----------------
__global__ void k_values(const f16* __restrict__ hs, const float* __restrict__ w_val,
                         const float* __restrict__ b_val, float* __restrict__ outv) {
  int t = blockIdx.x * 4 + (threadIdx.x >> 6);
  int l = threadIdx.x & 63;
  const f16* row = hs + (size_t)t * 1024 + l * 16;
  const float* wv = w_val + l * 16;
  float s = 0.f;
#pragma unroll
  for (int i = 0; i < 16; ++i) s += (float)row[i] * wv[i];
#pragma unroll
  for (int d = 1; d < 64; d <<= 1) s += __shfl_xor(s, d);
  if (l == 0) outv[t] = s + b_val[0];
}

// ---------------- softmax ----------------
__global__ void k_softmax(float* __restrict__ out) {
  int t = blockIdx.x * 4 + (threadIdx.x >> 6);
  int l = threadIdx.x & 63;
  float* row = out + (size_t)t * 512;
  float v[8];
  float m = -1e30f;
#pragma unroll
  for (int i = 0; i < 8; ++i) { v[i] = row[l + 64 * i]; m = fmaxf(m, v[i]); }
#pragma unroll
  for (int d = 1; d < 64; d <<= 1) m = fmaxf(m, __shfl_xor(m, d));
  float s = 0.f;
#pragma unroll
  for (int i = 0; i < 8; ++i) { v[i] = __expf(v[i] - m); s += v[i]; }
#pragma unroll
  for (int d = 1; d < 64; d <<= 1) s += __shfl_xor(s, d);
  float inv = 1.f / s;
#pragma unroll
  for (int i = 0; i < 8; ++i) row[l + 64 * i] = v[i] * inv;
}

extern "C" void kernel_launch(void* const* d_in, const int* in_sizes, int n_in,
                              void* d_out, int out_size, void* d_ws, size_t ws_size,
                              hipStream_t stream) {
  const float* x      = (const float*)d_in[0];
  const float* w_ih0  = (const float*)d_in[1];
  const float* w_hh0  = (const float*)d_in[2];
  const float* b_ih0  = (const float*)d_in[3];
  const float* b_hh0  = (const float*)d_in[4];
  const float* w_ih1  = (const float*)d_in[5];
  const float* w_hh1  = (const float*)d_in[6];
  const float* b_ih1  = (const float*)d_in[7];
  const float* b_hh1  = (const float*)d_in[8];
  const float* w_pol  = (const float*)d_in[9];
  const float* b_pol  = (const float*)d_in[10];
  const float* w_val  = (const float*)d_in[11];
  const float* b_val  = (const float*)d_in[12];

  char* ws = (char*)d_ws;
  f16*      Zx   = (f16*)(ws + OFF_ZX);
  f16*      hs   = (f16*)(ws + OFF_HS);
  uint64_t* R0A  = (uint64_t*)(ws + OFF_R0A);
  uint64_t* R0B  = (uint64_t*)(ws + OFF_R0B);
  uint64_t* R1A  = (uint64_t*)(ws + OFF_R1A);
  uint64_t* ZR   = (uint64_t*)(ws + OFF_ZR);
  uint32_t* PG0  = (uint32_t*)(ws + OFF_PG0);
  uint32_t* PG1  = (uint32_t*)(ws + OFF_PG1);
  uint32_t* XC   = (uint32_t*)(ws + OFF_XC);
  float*    out  = (float*)d_out;

  k_init<<<256, 256, 0, stream>>>((uint64_t*)(ws + OFF_R0A));
  // Zx0 = x @ w_ih0^T + b_ih0 + b_hh0 : M=8192, N=4096, K=512
  k_gemm<false, true><<<dim3(32, 64), 256, 0, stream>>>(
      (const void*)x, w_ih0, b_ih0, b_hh0, (void*)Zx, 4096, 512, 512);
  k_serial<<<256, 1024, 0, stream>>>(Zx, w_hh0, w_ih1, w_hh1, b_ih1, b_hh1, hs,
                                     R0A, R0B, R1A, ZR, PG0, PG1, XC);
  // policy logits = hs @ w_pol^T + b_pol : M=8192, N=512, K=1024 -> d_out (f32)
  k_gemm<true, false><<<dim3(4, 64), 256, 0, stream>>>(
      (const void*)hs, w_pol, b_pol, nullptr, (void*)out, 512, 1024, 1024);
  k_values<<<2048, 256, 0, stream>>>(hs, w_val, b_val, out + (size_t)8192 * 512);
  k_softmax<<<2048, 256, 0, stream>>>(out);
}

// Round 8
// 22049.091 us; speedup vs baseline: 1.5852x; 1.5852x over previous
//
#include <hip/hip_runtime.h>
#include <stdint.h>
#include <stddef.h>

typedef _Float16 f16;
typedef _Float16 half2_t __attribute__((ext_vector_type(2)));
typedef _Float16 half8_t __attribute__((ext_vector_type(8)));
typedef float   float4_t __attribute__((ext_vector_type(4)));
typedef float   float2_t __attribute__((ext_vector_type(2)));

#define T_STEPS 8192

// ---------------- workspace layout (bytes) ----------------
#define OFF_ZX   ((size_t)0)                    // Zx0 f16 [8192][4096]        = 67108864
#define OFF_HS   ((size_t)67108864)             // hs  f16 [8192][1024]        = 16777216
#define OFF_R0A  ((size_t)83886080)             // h0  u64[8 rep][8 slot][512] = 262144  (L0 <-> L0)
#define OFF_R0B  (OFF_R0A + 262144)             // h0  u64[8 rep][16][512]     = 524288  (L0 -> G1X)
#define OFF_R1A  (OFF_R0B + 524288)             // h1  u64[8 rep][8][512]      = 262144  (G1 <-> G1)
#define OFF_ZR   (OFF_R1A + 262144)             // z1x u64[4 rep][16][4096]    = 2097152 (G1X -> G1, f32)
#define OFF_PG0  (OFF_ZR + 2097152)             // prog0 u32[128] x16 stride   = 8192
#define OFF_PG1  (OFF_PG0 + 8192)               // prog1 u32[64]  x16 stride   = 4096
#define ZERO_BYTES ((size_t)(OFF_PG1 + 4096 - OFF_R0A))   // 3,158,016

__device__ __forceinline__ uint32_t packh(float a, float b) {
  half2_t h; h.x = (_Float16)a; h.y = (_Float16)b;
  return __builtin_bit_cast(uint32_t, h);
}
__device__ __forceinline__ float fdot2w(uint32_t w, uint32_t h, float c) {
#if __has_builtin(__builtin_amdgcn_fdot2)
  return __builtin_amdgcn_fdot2(__builtin_bit_cast(half2_t, w),
                                __builtin_bit_cast(half2_t, h), c, false);
#else
  half2_t a = __builtin_bit_cast(half2_t, w);
  half2_t b = __builtin_bit_cast(half2_t, h);
  return c + (float)a.x * (float)b.x + (float)a.y * (float)b.y;
#endif
}
__device__ __forceinline__ uint64_t ald64(const uint64_t* p) {
  return __hip_atomic_load(p, __ATOMIC_RELAXED, __HIP_MEMORY_SCOPE_AGENT);
}
__device__ __forceinline__ void ast64(uint64_t* p, uint64_t v) {
  __hip_atomic_store(p, v, __ATOMIC_RELAXED, __HIP_MEMORY_SCOPE_AGENT);
}
__device__ __forceinline__ uint32_t ald32(const uint32_t* p) {
  return __hip_atomic_load(p, __ATOMIC_RELAXED, __HIP_MEMORY_SCOPE_AGENT);
}
__device__ __forceinline__ void ast32(uint32_t* p, uint32_t v) {
  __hip_atomic_store(p, v, __ATOMIC_RELAXED, __HIP_MEMORY_SCOPE_AGENT);
}
// hot poll: serial-critical rings, pure agent loads, no backoff
__device__ __forceinline__ uint32_t poll_a(const uint64_t* p, uint32_t tag) {
  for (;;) {
    uint64_t v = ald64(p);
    if ((uint32_t)(v >> 32) == tag) return (uint32_t)v;
  }
}
// slack poll: pipelined streams, light backoff
__device__ __forceinline__ uint32_t poll_s(const uint64_t* p, uint32_t tag) {
  int it = 0;
  for (;;) {
    uint64_t v = ald64(p);
    if ((uint32_t)(v >> 32) == tag) return (uint32_t)v;
    if ((++it & 15) == 15) __builtin_amdgcn_s_sleep(1);
  }
}
__device__ __forceinline__ float sigf(float x) { return 1.f / (1.f + __expf(-x)); }
__device__ __forceinline__ float tanhf_(float x) { return 2.f * sigf(2.f * x) - 1.f; }
__device__ __forceinline__ float bitsf(uint32_t u) { return __builtin_bit_cast(float, u); }
__device__ __forceinline__ uint32_t fbits(float f) { return __builtin_bit_cast(uint32_t, f); }

__global__ void k_init(uint64_t* __restrict__ Z) {
  size_t n = ZERO_BYTES / 8;
  for (size_t i = blockIdx.x * blockDim.x + threadIdx.x; i < n;
       i += (size_t)gridDim.x * blockDim.x)
    Z[i] = 0ull;
}

// ---------------- generic 128x128 MFMA f16 GEMM (unchanged) ----------------
template <bool A16, bool OUT16>
__global__ __launch_bounds__(256) void k_gemm(const void* __restrict__ Ap,
                                              const float* __restrict__ B,
                                              const float* __restrict__ bias0,
                                              const float* __restrict__ bias1,
                                              void* __restrict__ Cp,
                                              int N, int K, int lda) {
  __shared__ __align__(16) f16 As[128 * 40];
  __shared__ __align__(16) f16 Bs[128 * 40];
  int bn = blockIdx.x * 128, bm = blockIdx.y * 128;
  int tid = threadIdx.x;
  int w = tid >> 6, l = tid & 63;
  int m0w = (w >> 1) * 64, n0w = (w & 1) * 64;
  int lr = l & 15, q = l >> 4;
  int srow = tid >> 1, skoff = (tid & 1) * 16;

  float4_t acc[4][4];
#pragma unroll
  for (int i = 0; i < 4; ++i)
#pragma unroll
    for (int j = 0; j < 4; ++j) acc[i][j] = (float4_t){0.f, 0.f, 0.f, 0.f};

  for (int kt = 0; kt < K; kt += 32) {
    __syncthreads();
    if (A16) {
      const f16* Ah = (const f16*)Ap + (size_t)(bm + srow) * lda + kt + skoff;
      uint4 u0 = *(const uint4*)Ah;
      uint4 u1 = *(const uint4*)(Ah + 8);
      *(uint4*)&As[srow * 40 + skoff] = u0;
      *(uint4*)&As[srow * 40 + skoff + 8] = u1;
    } else {
      const float* Af = (const float*)Ap + (size_t)(bm + srow) * lda + kt + skoff;
      const float4_t* A4 = (const float4_t*)Af;
      float4_t f0 = A4[0], f1 = A4[1], f2 = A4[2], f3 = A4[3];
      half8_t h0 = {(f16)f0.x, (f16)f0.y, (f16)f0.z, (f16)f0.w,
                    (f16)f1.x, (f16)f1.y, (f16)f1.z, (f16)f1.w};
      half8_t h1 = {(f16)f2.x, (f16)f2.y, (f16)f2.z, (f16)f2.w,
                    (f16)f3.x, (f16)f3.y, (f16)f3.z, (f16)f3.w};
      *(half8_t*)&As[srow * 40 + skoff] = h0;
      *(half8_t*)&As[srow * 40 + skoff + 8] = h1;
    }
    {
      const float* Bf = B + (size_t)(bn + srow) * K + kt + skoff;
      const float4_t* B4 = (const float4_t*)Bf;
      float4_t f0 = B4[0], f1 = B4[1], f2 = B4[2], f3 = B4[3];
      half8_t h0 = {(f16)f0.x, (f16)f0.y, (f16)f0.z, (f16)f0.w,
                    (f16)f1.x, (f16)f1.y, (f16)f1.z, (f16)f1.w};
      half8_t h1 = {(f16)f2.x, (f16)f2.y, (f16)f2.z, (f16)f2.w,
                    (f16)f3.x, (f16)f3.y, (f16)f3.z, (f16)f3.w};
      *(half8_t*)&Bs[srow * 40 + skoff] = h0;
      *(half8_t*)&Bs[srow * 40 + skoff + 8] = h1;
    }
    __syncthreads();
    half8_t af[4], bf[4];
#pragma unroll
    for (int i = 0; i < 4; ++i) af[i] = *(const half8_t*)&As[(m0w + 16 * i + lr) * 40 + q * 8];
#pragma unroll
    for (int j = 0; j < 4; ++j) bf[j] = *(const half8_t*)&Bs[(n0w + 16 * j + lr) * 40 + q * 8];
#pragma unroll
    for (int i = 0; i < 4; ++i)
#pragma unroll
      for (int j = 0; j < 4; ++j)
        acc[i][j] = __builtin_amdgcn_mfma_f32_16x16x32_f16(af[i], bf[j], acc[i][j], 0, 0, 0);
  }
#pragma unroll
  for (int j = 0; j < 4; ++j) {
    int n = bn + n0w + 16 * j + lr;
    float bv = bias0 ? bias0[n] : 0.f;
    if (bias1) bv += bias1[n];
#pragma unroll
    for (int i = 0; i < 4; ++i) {
#pragma unroll
      for (int r = 0; r < 4; ++r) {
        int m = bm + m0w + 16 * i + q * 4 + r;
        float v = acc[i][j][r] + bv;
        if (OUT16) ((f16*)Cp)[(size_t)m * N + n] = (f16)v;
        else       ((float*)Cp)[(size_t)m * N + n] = v;
      }
    }
  }
}

// ================= L0: layer-0 serial, 64 blocks. Wave w owns output O+w =================
// wr[32] = 4 gate rows x 8 f16-pairs per lane -> fits the 64-VGPR wg=1024 cap.
__device__ __forceinline__ void run_l0(int r, const f16* Zx, const float* whh0,
                                       uint64_t* R0A, uint64_t* R0B,
                                       const uint32_t* prog0) {
  __shared__ uint32_t hL[512];
  __shared__ uint32_t zxL[64];
  __shared__ float pf[16];
  int tid = threadIdx.x, w = tid >> 6, l = tid & 63;
  int O = 16 * r;
  uint32_t wr[32];
#pragma unroll
  for (int g = 0; g < 4; ++g) {
    size_t R = (size_t)(1024 * g + O + w) * 1024;
#pragma unroll
    for (int p = 0; p < 8; ++p) {
      int k = l + 64 * p;
      float2_t u = *(const float2_t*)&whh0[R + 2 * k];
      wr[g * 8 + p] = packh(u.x, u.y);
    }
  }
  float c0 = 0.f;
  uint32_t zb = 0;
  if (w == 8) zb = fbits((float)Zx[(size_t)1024 * (l >> 4) + O + (l & 15)]);

  for (int t = 0; t < T_STEPS; ++t) {
    if (w == 8) zxL[l] = zb;
    if (w < 8)
      hL[tid] = poll_a(&R0A[((size_t)(r & 7) * 8 + (size_t)(t & 7)) * 512 + tid],
                       (uint32_t)t);
    if (w == 12 && l == 0 && (t & 3) == 0 && t >= 8) {
      // throttle vs G1X consumption of R0B (depth 16; lag margin 6)
      const uint32_t* pa = prog0 + r * 16;
      const uint32_t* pb = prog0 + (64 + r) * 16;
      while ((int)ald32(pa) < t - 6 || (int)ald32(pb) < t - 6)
        __builtin_amdgcn_s_sleep(2);
    }
    __syncthreads();
    if (w == 8 && t + 1 < T_STEPS)
      zb = fbits((float)Zx[(size_t)(t + 1) * 4096 + 1024 * (l >> 4) + O + (l & 15)]);
    uint32_t hw[8];
#pragma unroll
    for (int p = 0; p < 8; ++p) hw[p] = hL[l + 64 * p];
    float a0 = 0.f, a1 = 0.f, a2 = 0.f, a3 = 0.f;
#pragma unroll
    for (int p = 0; p < 8; ++p) {
      a0 = fdot2w(wr[p], hw[p], a0);
      a1 = fdot2w(wr[8 + p], hw[p], a1);
      a2 = fdot2w(wr[16 + p], hw[p], a2);
      a3 = fdot2w(wr[24 + p], hw[p], a3);
    }
#pragma unroll
    for (int d = 1; d < 64; d <<= 1) {
      a0 += __shfl_xor(a0, d); a1 += __shfl_xor(a1, d);
      a2 += __shfl_xor(a2, d); a3 += __shfl_xor(a3, d);
    }
    if (l == 0) {
      float zi = a0 + bitsf(zxL[w]);
      float zf = a1 + bitsf(zxL[16 + w]);
      float zg = a2 + bitsf(zxL[32 + w]);
      float zo = a3 + bitsf(zxL[48 + w]);
      float ig = sigf(zi), fg = sigf(zf), gg = tanhf_(zg), og = sigf(zo);
      c0 = fg * c0 + ig * gg;
      pf[w] = og * tanhf_(c0);
    }
    __syncthreads();
    uint32_t tg = (uint32_t)(t + 1);
    if (w == 15) {
      int p = l & 7, rep = l >> 3;
      uint64_t val = ((uint64_t)tg << 32) | (uint64_t)packh(pf[2 * p], pf[2 * p + 1]);
      ast64(&R0A[((size_t)rep * 8 + (size_t)(tg & 7)) * 512 + 8 * r + p], val);
    } else if (w == 14) {
      int p = l & 7, rep = l >> 3;
      uint64_t val = ((uint64_t)tg << 32) | (uint64_t)packh(pf[2 * p], pf[2 * p + 1]);
      ast64(&R0B[((size_t)rep * 16 + (size_t)(tg & 15)) * 512 + 8 * r + p], val);
    }
  }
}

// ================= G1: layer-1 serial, 64 blocks. Wave w owns output O+w =================
__device__ __forceinline__ void run_g1(int q, const float* whh1, const float* b_ih1,
                                       const float* b_hh1, uint64_t* R1A,
                                       const uint64_t* ZR, f16* hs,
                                       uint32_t* prog1) {
  __shared__ uint32_t hL[512];
  __shared__ uint32_t zxL[64];
  __shared__ float pf[16];
  int tid = threadIdx.x, w = tid >> 6, l = tid & 63;
  int O = 16 * q;
  uint32_t wr[32];
#pragma unroll
  for (int g = 0; g < 4; ++g) {
    size_t R = (size_t)(1024 * g + O + w) * 1024;
#pragma unroll
    for (int p = 0; p < 8; ++p) {
      int k = l + 64 * p;
      float2_t u = *(const float2_t*)&whh1[R + 2 * k];
      wr[g * 8 + p] = packh(u.x, u.y);
    }
  }
  float c1 = 0.f;
  float bv0 = 0.f, bv1 = 0.f, bv2 = 0.f, bv3 = 0.f;
  if (l == 0) {
    int base = O + w;
    bv0 = b_ih1[base] + b_hh1[base];
    bv1 = b_ih1[1024 + base] + b_hh1[1024 + base];
    bv2 = b_ih1[2048 + base] + b_hh1[2048 + base];
    bv3 = b_ih1[3072 + base] + b_hh1[3072 + base];
  }

  for (int t = 0; t < T_STEPS; ++t) {
    if (w < 8) {
      hL[tid] = poll_a(&R1A[((size_t)(q & 7) * 8 + (size_t)(t & 7)) * 512 + tid],
                       (uint32_t)t);
    } else if (w == 9) {  // z1x stream (f32 payload): 64 entries for this block
      zxL[l] = poll_s(&ZR[((size_t)(q & 3) * 16 + (size_t)((t + 1) & 15)) * 4096
                          + 1024 * (l >> 4) + O + (l & 15)],
                      (uint32_t)(t + 1));
    }
    __syncthreads();
    if (tid == 640) ast32(prog1 + q * 16, (uint32_t)(t + 1));
    uint32_t hw[8];
#pragma unroll
    for (int p = 0; p < 8; ++p) hw[p] = hL[l + 64 * p];
    float a0 = 0.f, a1 = 0.f, a2 = 0.f, a3 = 0.f;
#pragma unroll
    for (int p = 0; p < 8; ++p) {
      a0 = fdot2w(wr[p], hw[p], a0);
      a1 = fdot2w(wr[8 + p], hw[p], a1);
      a2 = fdot2w(wr[16 + p], hw[p], a2);
      a3 = fdot2w(wr[24 + p], hw[p], a3);
    }
#pragma unroll
    for (int d = 1; d < 64; d <<= 1) {
      a0 += __shfl_xor(a0, d); a1 += __shfl_xor(a1, d);
      a2 += __shfl_xor(a2, d); a3 += __shfl_xor(a3, d);
    }
    if (l == 0) {
      float zi = a0 + bitsf(zxL[w]) + bv0;
      float zf = a1 + bitsf(zxL[16 + w]) + bv1;
      float zg = a2 + bitsf(zxL[32 + w]) + bv2;
      float zo = a3 + bitsf(zxL[48 + w]) + bv3;
      float ig = sigf(zi), fg = sigf(zf), gg = tanhf_(zg), og = sigf(zo);
      c1 = fg * c1 + ig * gg;
      pf[w] = og * tanhf_(c1);
    }
    __syncthreads();
    uint32_t tg = (uint32_t)(t + 1);
    if (w == 15) {
      int p = l & 7, rep = l >> 3;
      uint64_t val = ((uint64_t)tg << 32) | (uint64_t)packh(pf[2 * p], pf[2 * p + 1]);
      ast64(&R1A[((size_t)rep * 8 + (size_t)(tg & 7)) * 512 + 8 * q + p], val);
    } else if (w == 14 && l < 8) {
      ((uint32_t*)hs)[(size_t)t * 512 + 8 * q + l] = packh(pf[2 * l], pf[2 * l + 1]);
    }
  }
}

// ================= G1X: z1x = w_ih1 @ h0 + b, 2 cohorts x 64 blocks =================
// Block covers 64 rows (wave w: rows 64s+4w .. 64s+4w+3), every other phase.
__device__ __forceinline__ void run_g1x(int u, const float* wih1,
                                        const float* b_ih1, const float* b_hh1,
                                        const uint64_t* R0B, uint64_t* ZR,
                                        uint32_t* prog0, const uint32_t* prog1) {
  __shared__ uint32_t hL[512];
  int tid = threadIdx.x, w = tid >> 6, l = tid & 63;
  int cgrp = u >> 6, s = u & 63;
  uint32_t wr[32];
  float bb0, bb1, bb2, bb3;
  {
    int row0 = 64 * s + 4 * w;
    bb0 = b_ih1[row0] + b_hh1[row0];
    bb1 = b_ih1[row0 + 1] + b_hh1[row0 + 1];
    bb2 = b_ih1[row0 + 2] + b_hh1[row0 + 2];
    bb3 = b_ih1[row0 + 3] + b_hh1[row0 + 3];
#pragma unroll
    for (int j = 0; j < 4; ++j) {
      size_t R = (size_t)(row0 + j) * 1024;
#pragma unroll
      for (int p = 0; p < 8; ++p) {
        int k = l + 64 * p;
        float2_t uu = *(const float2_t*)&wih1[R + 2 * k];
        wr[j * 8 + p] = packh(uu.x, uu.y);
      }
    }
  }
  for (int t = cgrp; t < T_STEPS; t += 2) {
    if (w < 8)
      hL[tid] = poll_s(&R0B[((size_t)(s & 7) * 16 + (size_t)((t + 1) & 15)) * 512 + tid],
                       (uint32_t)(t + 1));
    if (w == 12 && l == 0) {  // throttle vs G1 consumption of ZR (depth 16; margin 8)
      int q0 = 4 * (s & 15);
#pragma unroll
      for (int i = 0; i < 4; ++i)
        while ((int)ald32(prog1 + (q0 + i) * 16) < t - 8) __builtin_amdgcn_s_sleep(2);
    }
    __syncthreads();
    if (tid == 640) ast32(prog0 + u * 16, (uint32_t)(t + 1));
    uint32_t hw[8];
#pragma unroll
    for (int p = 0; p < 8; ++p) hw[p] = hL[l + 64 * p];
    float a0 = 0.f, a1 = 0.f, a2 = 0.f, a3 = 0.f;
#pragma unroll
    for (int p = 0; p < 8; ++p) {
      a0 = fdot2w(wr[p], hw[p], a0);
      a1 = fdot2w(wr[8 + p], hw[p], a1);
      a2 = fdot2w(wr[16 + p], hw[p], a2);
      a3 = fdot2w(wr[24 + p], hw[p], a3);
    }
#pragma unroll
    for (int d = 1; d < 64; d <<= 1) {
      a0 += __shfl_xor(a0, d); a1 += __shfl_xor(a1, d);
      a2 += __shfl_xor(a2, d); a3 += __shfl_xor(a3, d);
    }
    if (l < 16) {
      int j = l & 3, rep = l >> 2;
      float zv = (j == 0 ? a0 : j == 1 ? a1 : j == 2 ? a2 : a3)
               + (j == 0 ? bb0 : j == 1 ? bb1 : j == 2 ? bb2 : bb3);
      uint64_t val = ((uint64_t)(uint32_t)(t + 1) << 32) | (uint64_t)fbits(zv);
      ast64(&ZR[((size_t)rep * 16 + (size_t)((t + 1) & 15)) * 4096 + 64 * s + 4 * w + j],
            val);
    }
    __syncthreads();
  }
}

__global__ __launch_bounds__(1024, 1) void k_serial(
    const f16* __restrict__ Zx, const float* __restrict__ whh0,
    const float* __restrict__ wih1, const float* __restrict__ whh1,
    const float* __restrict__ b_ih1, const float* __restrict__ b_hh1,
    f16* __restrict__ hs, uint64_t* __restrict__ R0A, uint64_t* __restrict__ R0B,
    uint64_t* __restrict__ R1A, uint64_t* __restrict__ ZR,
    uint32_t* __restrict__ prog0, uint32_t* __restrict__ prog1) {
  int b = blockIdx.x;
  if (b < 64)       run_l0(b, Zx, whh0, R0A, R0B, prog0);
  else if (b < 128) run_g1(b - 64, whh1, b_ih1, b_hh1, R1A, ZR, hs, prog1);
  else              run_g1x(b - 128, wih1, b_ih1, b_hh1, R0B, ZR, prog0, prog1);
}

// ---------------- value head ----------------
__global__ void k_values(const f16* __restrict__ hs, const float* __restrict__ w_val,
                         const float* __restrict__ b_val, float* __restrict__ outv) {
  int t = blockIdx.x * 4 + (threadIdx.x >> 6);
  int l = threadIdx.x & 63;
  const f16* row = hs + (size_t)t * 1024 + l * 16;
  const float* wv = w_val + l * 16;
  float s = 0.f;
#pragma unroll
  for (int i = 0; i < 16; ++i) s += (float)row[i] * wv[i];
#pragma unroll
  for (int d = 1; d < 64; d <<= 1) s += __shfl_xor(s, d);
  if (l == 0) outv[t] = s + b_val[0];
}

// ---------------- softmax ----------------
__global__ void k_softmax(float* __restrict__ out) {
  int t = blockIdx.x * 4 + (threadIdx.x >> 6);
  int l = threadIdx.x & 63;
  float* row = out + (size_t)t * 512;
  float v[8];
  float m = -1e30f;
#pragma unroll
  for (int i = 0; i < 8; ++i) { v[i] = row[l + 64 * i]; m = fmaxf(m, v[i]); }
#pragma unroll
  for (int d = 1; d < 64; d <<= 1) m = fmaxf(m, __shfl_xor(m, d));
  float s = 0.f;
#pragma unroll
  for (int i = 0; i < 8; ++i) { v[i] = __expf(v[i] - m); s += v[i]; }
#pragma unroll
  for (int d = 1; d < 64; d <<= 1) s += __shfl_xor(s, d);
  float inv = 1.f / s;
#pragma unroll
  for (int i = 0; i < 8; ++i) row[l + 64 * i] = v[i] * inv;
}

extern "C" void kernel_launch(void* const* d_in, const int* in_sizes, int n_in,
                              void* d_out, int out_size, void* d_ws, size_t ws_size,
                              hipStream_t stream) {
  const float* x      = (const float*)d_in[0];
  const float* w_ih0  = (const float*)d_in[1];
  const float* w_hh0  = (const float*)d_in[2];
  const float* b_ih0  = (const float*)d_in[3];
  const float* b_hh0  = (const float*)d_in[4];
  const float* w_ih1  = (const float*)d_in[5];
  const float* w_hh1  = (const float*)d_in[6];
  const float* b_ih1  = (const float*)d_in[7];
  const float* b_hh1  = (const float*)d_in[8];
  const float* w_pol  = (const float*)d_in[9];
  const float* b_pol  = (const float*)d_in[10];
  const float* w_val  = (const float*)d_in[11];
  const float* b_val  = (const float*)d_in[12];

  char* ws = (char*)d_ws;
  f16*      Zx   = (f16*)(ws + OFF_ZX);
  f16*      hs   = (f16*)(ws + OFF_HS);
  uint64_t* R0A  = (uint64_t*)(ws + OFF_R0A);
  uint64_t* R0B  = (uint64_t*)(ws + OFF_R0B);
  uint64_t* R1A  = (uint64_t*)(ws + OFF_R1A);
  uint64_t* ZR   = (uint64_t*)(ws + OFF_ZR);
  uint32_t* PG0  = (uint32_t*)(ws + OFF_PG0);
  uint32_t* PG1  = (uint32_t*)(ws + OFF_PG1);
  float*    out  = (float*)d_out;

  k_init<<<256, 256, 0, stream>>>((uint64_t*)(ws + OFF_R0A));
  // Zx0 = x @ w_ih0^T + b_ih0 + b_hh0 : M=8192, N=4096, K=512
  k_gemm<false, true><<<dim3(32, 64), 256, 0, stream>>>(
      (const void*)x, w_ih0, b_ih0, b_hh0, (void*)Zx, 4096, 512, 512);
  k_serial<<<256, 1024, 0, stream>>>(Zx, w_hh0, w_ih1, w_hh1, b_ih1, b_hh1, hs,
                                     R0A, R0B, R1A, ZR, PG0, PG1);
  // policy logits = hs @ w_pol^T + b_pol : M=8192, N=512, K=1024 -> d_out (f32)
  k_gemm<true, false><<<dim3(4, 64), 256, 0, stream>>>(
      (const void*)hs, w_pol, b_pol, nullptr, (void*)out, 512, 1024, 1024);
  k_values<<<2048, 256, 0, stream>>>(hs, w_val, b_val, out + (size_t)8192 * 512);
  k_softmax<<<2048, 256, 0, stream>>>(out);
}